// Round 1
// baseline (450.080 us; speedup 1.0000x reference)
//
#include <hip/hip_runtime.h>
#include <math.h>

#define NVIEWS 1024
#define SS 64
#define DD 256

typedef __bf16 bf16x8 __attribute__((ext_vector_type(8)));
typedef float f32x4 __attribute__((ext_vector_type(4)));
typedef unsigned short us4 __attribute__((ext_vector_type(4)));

// LDS layout (bytes). Strides chosen so ds_read_b128 is 16B-aligned and
// row-to-row bank shift is 4 banks -> worst case 2-way conflict (free, m136).
#define STR_W 264   // elements, for [64][256] bf16 buffers (528B row = 33*16)
#define STR_T 72    // elements, for [256][64] vpT and [64][64] P (144B = 9*16)
#define OFF_A 0      // sQP (33792B) then sVT (36864B)
#define OFF_B 36864  // sKP (33792B) then attn-out (33792B)
#define OFF_P 70656  // P (9216B)
#define LDS_TOTAL 79872

__device__ __forceinline__ unsigned short f2bf(float f) {
    union { float f; unsigned int u; } x; x.f = f;
    return (unsigned short)((x.u + 0x7fffu + ((x.u >> 16) & 1u)) >> 16);
}

__global__ void prep_kernel(const float* __restrict__ Wq, const float* __restrict__ Wk,
                            const float* __restrict__ Wv, const float* __restrict__ Wo,
                            unsigned short* __restrict__ ws) {
    int idx = blockIdx.x * blockDim.x + threadIdx.x;  // 65536 threads
    if (idx < 65536) {
        ws[idx]          = f2bf(Wq[idx]);
        ws[idx + 65536]  = f2bf(Wk[idx]);
        ws[idx + 131072] = f2bf(Wv[idx]);
        ws[idx + 196608] = f2bf(Wo[idx]);
    }
    if (idx < SS * DD) {
        float* pe = (float*)(ws + 262144);
        int s = idx >> 8, j = idx & 255;
        // angle = s / 10000^(2*(j/2)/256) = s * e^(-(j/2)/128 * ln(10000))
        float ang = (float)s * expf(-((float)(j >> 1)) * (9.210340371976184f / 128.0f));
        pe[idx] = (j & 1) ? cosf(ang) : sinf(ang);
    }
}

__global__ __launch_bounds__(256, 2)
void attn_kernel(const float* __restrict__ qg_, const float* __restrict__ kg_,
                 const float* __restrict__ vg_, const unsigned short* __restrict__ ws,
                 const float* __restrict__ bo, float* __restrict__ outg) {
    __shared__ __attribute__((aligned(16))) char smem[LDS_TOTAL];
    unsigned short* sA = (unsigned short*)(smem + OFF_A);  // qp, later vp^T
    unsigned short* sB = (unsigned short*)(smem + OFF_B);  // kp, later attn-out
    unsigned short* sP = (unsigned short*)(smem + OFF_P);  // softmax probs

    const unsigned short* Wq = ws;
    const unsigned short* Wk = ws + 65536;
    const unsigned short* Wv = ws + 131072;
    const unsigned short* Wo = ws + 196608;
    const float* pe = (const float*)(ws + 262144);

    const int tid  = threadIdx.x;
    const int w    = tid >> 6;        // wave 0..3
    const int lane = tid & 63;
    const int quad = lane >> 4;
    const int l    = lane & 15;
    const int n0   = w << 6;          // this wave's 64-wide N chunk
    const int koff = quad << 3;       // k offset within fragment

    const size_t base = (size_t)blockIdx.x * (SS * DD);
    const float* qg = qg_ + base;
    const float* kg = kg_ + base;
    const float* vg = vg_ + base;
    float* og = outg + base;

    // ---- projection: acc[mt][nt] = X[64x256] @ W^T (W row-major [n][k] bf16) ----
    auto project = [&](const float* __restrict__ X, const unsigned short* __restrict__ W,
                       f32x4 (&acc)[4][4]) {
        for (int k0 = 0; k0 < DD; k0 += 32) {
            bf16x8 af[4], bfr[4];
            #pragma unroll
            for (int mt = 0; mt < 4; ++mt) {
                const float4* p = (const float4*)(X + (mt * 16 + l) * DD + k0 + koff);
                float4 a0 = p[0], a1 = p[1];
                union { unsigned short u[8]; bf16x8 v; } t;
                t.u[0] = f2bf(a0.x); t.u[1] = f2bf(a0.y); t.u[2] = f2bf(a0.z); t.u[3] = f2bf(a0.w);
                t.u[4] = f2bf(a1.x); t.u[5] = f2bf(a1.y); t.u[6] = f2bf(a1.z); t.u[7] = f2bf(a1.w);
                af[mt] = t.v;
            }
            #pragma unroll
            for (int nt = 0; nt < 4; ++nt)
                bfr[nt] = *(const bf16x8*)(W + (n0 + nt * 16 + l) * DD + k0 + koff);
            #pragma unroll
            for (int mt = 0; mt < 4; ++mt)
                #pragma unroll
                for (int nt = 0; nt < 4; ++nt)
                    acc[mt][nt] = __builtin_amdgcn_mfma_f32_16x16x32_bf16(af[mt], bfr[nt], acc[mt][nt], 0, 0, 0);
        }
    };

    f32x4 acc[4][4];
    #pragma unroll
    for (int i = 0; i < 4; ++i)
        #pragma unroll
        for (int j = 0; j < 4; ++j) acc[i][j] = (f32x4){0.f, 0.f, 0.f, 0.f};

    // ---- step 1: kp = k @ Wk^T + pe  -> sB [64][STR_W] ----
    project(kg, Wk, acc);
    #pragma unroll
    for (int mt = 0; mt < 4; ++mt)
        #pragma unroll
        for (int nt = 0; nt < 4; ++nt) {
            int col = n0 + nt * 16 + l;
            #pragma unroll
            for (int r = 0; r < 4; ++r) {
                int row = mt * 16 + (quad << 2) + r;
                sB[row * STR_W + col] = f2bf(acc[mt][nt][r] + pe[row * DD + col]);
            }
        }

    // ---- step 2: qp = q @ Wq^T + pe  -> sA [64][STR_W] ----
    #pragma unroll
    for (int i = 0; i < 4; ++i)
        #pragma unroll
        for (int j = 0; j < 4; ++j) acc[i][j] = (f32x4){0.f, 0.f, 0.f, 0.f};
    project(qg, Wq, acc);
    #pragma unroll
    for (int mt = 0; mt < 4; ++mt)
        #pragma unroll
        for (int nt = 0; nt < 4; ++nt) {
            int col = n0 + nt * 16 + l;
            #pragma unroll
            for (int r = 0; r < 4; ++r) {
                int row = mt * 16 + (quad << 2) + r;
                sA[row * STR_W + col] = f2bf(acc[mt][nt][r] + pe[row * DD + col]);
            }
        }

    __syncthreads();  // B1: qp/kp visible

    // ---- step 3: S = qp @ kp^T, wave owns 16 q-rows x all 64 keys; softmax in-wave ----
    {
        f32x4 sacc[4];
        #pragma unroll
        for (int nt = 0; nt < 4; ++nt) sacc[nt] = (f32x4){0.f, 0.f, 0.f, 0.f};
        for (int k0 = 0; k0 < DD; k0 += 32) {
            bf16x8 a = *(const bf16x8*)(sA + (w * 16 + l) * STR_W + k0 + koff);
            #pragma unroll
            for (int nt = 0; nt < 4; ++nt) {
                bf16x8 b = *(const bf16x8*)(sB + (nt * 16 + l) * STR_W + k0 + koff);
                sacc[nt] = __builtin_amdgcn_mfma_f32_16x16x32_bf16(a, b, sacc[nt], 0, 0, 0);
            }
        }
        #pragma unroll
        for (int r = 0; r < 4; ++r) {
            float v0 = sacc[0][r] * 0.0625f, v1 = sacc[1][r] * 0.0625f;
            float v2 = sacc[2][r] * 0.0625f, v3 = sacc[3][r] * 0.0625f;
            float mx = fmaxf(fmaxf(v0, v1), fmaxf(v2, v3));
            #pragma unroll
            for (int d = 1; d <= 8; d <<= 1) mx = fmaxf(mx, __shfl_xor(mx, d));
            float e0 = __expf(v0 - mx), e1 = __expf(v1 - mx);
            float e2 = __expf(v2 - mx), e3 = __expf(v3 - mx);
            float sm = e0 + e1 + e2 + e3;
            #pragma unroll
            for (int d = 1; d <= 8; d <<= 1) sm += __shfl_xor(sm, d);
            float inv = 1.0f / sm;
            int row = w * 16 + (quad << 2) + r;
            sP[row * STR_T + l]      = f2bf(e0 * inv);
            sP[row * STR_T + 16 + l] = f2bf(e1 * inv);
            sP[row * STR_T + 32 + l] = f2bf(e2 * inv);
            sP[row * STR_T + 48 + l] = f2bf(e3 * inv);
        }
    }

    // ---- step 4: vp = v @ Wv^T + pe, written TRANSPOSED into sA as vpT [256][STR_T] ----
    #pragma unroll
    for (int i = 0; i < 4; ++i)
        #pragma unroll
        for (int j = 0; j < 4; ++j) acc[i][j] = (f32x4){0.f, 0.f, 0.f, 0.f};
    project(vg, Wv, acc);        // global reads + MFMA only; no LDS touched yet
    __syncthreads();             // B2: all S-reads of sA/sB done; sP complete
    #pragma unroll
    for (int mt = 0; mt < 4; ++mt)
        #pragma unroll
        for (int nt = 0; nt < 4; ++nt) {
            int col = n0 + nt * 16 + l;          // d index = vpT row
            int rbase = mt * 16 + (quad << 2);   // s index
            us4 pk;
            #pragma unroll
            for (int r = 0; r < 4; ++r)
                pk[r] = f2bf(acc[mt][nt][r] + pe[(rbase + r) * DD + col]);
            *(us4*)(sA + col * STR_T + rbase) = pk;  // 8B transpose-write
        }
    __syncthreads();  // B3: vpT visible

    // ---- step 5: out = P @ vp  (A=P from sP, B=vpT from sA) -> sB [64][STR_W] ----
    {
        f32x4 oacc[4][4];
        #pragma unroll
        for (int i = 0; i < 4; ++i)
            #pragma unroll
            for (int j = 0; j < 4; ++j) oacc[i][j] = (f32x4){0.f, 0.f, 0.f, 0.f};
        #pragma unroll
        for (int k0 = 0; k0 < 64; k0 += 32) {
            bf16x8 af[4], bfr[4];
            #pragma unroll
            for (int mt = 0; mt < 4; ++mt)
                af[mt] = *(const bf16x8*)(sP + (mt * 16 + l) * STR_T + k0 + koff);
            #pragma unroll
            for (int nt = 0; nt < 4; ++nt)
                bfr[nt] = *(const bf16x8*)(sA + (n0 + nt * 16 + l) * STR_T + k0 + koff);
            #pragma unroll
            for (int mt = 0; mt < 4; ++mt)
                #pragma unroll
                for (int nt = 0; nt < 4; ++nt)
                    oacc[mt][nt] = __builtin_amdgcn_mfma_f32_16x16x32_bf16(af[mt], bfr[nt], oacc[mt][nt], 0, 0, 0);
        }
        #pragma unroll
        for (int mt = 0; mt < 4; ++mt)
            #pragma unroll
            for (int nt = 0; nt < 4; ++nt) {
                int col = n0 + nt * 16 + l;
                #pragma unroll
                for (int r = 0; r < 4; ++r)
                    sB[(mt * 16 + (quad << 2) + r) * STR_W + col] = f2bf(oacc[mt][nt][r]);
            }
    }
    __syncthreads();  // B4: attn-out visible

    // ---- step 6: y = gelu(out @ Wo^T + bo) + q ----
    {
        f32x4 facc[4][4];
        #pragma unroll
        for (int i = 0; i < 4; ++i)
            #pragma unroll
            for (int j = 0; j < 4; ++j) facc[i][j] = (f32x4){0.f, 0.f, 0.f, 0.f};
        for (int k0 = 0; k0 < DD; k0 += 32) {
            bf16x8 af[4], bfr[4];
            #pragma unroll
            for (int mt = 0; mt < 4; ++mt)
                af[mt] = *(const bf16x8*)(sB + (mt * 16 + l) * STR_W + k0 + koff);
            #pragma unroll
            for (int nt = 0; nt < 4; ++nt)
                bfr[nt] = *(const bf16x8*)(Wo + (n0 + nt * 16 + l) * DD + k0 + koff);
            #pragma unroll
            for (int mt = 0; mt < 4; ++mt)
                #pragma unroll
                for (int nt = 0; nt < 4; ++nt)
                    facc[mt][nt] = __builtin_amdgcn_mfma_f32_16x16x32_bf16(af[mt], bfr[nt], facc[mt][nt], 0, 0, 0);
        }
        float bias[4];
        #pragma unroll
        for (int nt = 0; nt < 4; ++nt) bias[nt] = bo[n0 + nt * 16 + l];
        #pragma unroll
        for (int mt = 0; mt < 4; ++mt)
            #pragma unroll
            for (int nt = 0; nt < 4; ++nt) {
                int col = n0 + nt * 16 + l;
                #pragma unroll
                for (int r = 0; r < 4; ++r) {
                    int row = mt * 16 + (quad << 2) + r;
                    float y = facc[mt][nt][r] + bias[nt];
                    float g = 0.5f * y * (1.0f + erff(y * 0.7071067811865475f));
                    og[row * DD + col] = g + qg[row * DD + col];
                }
            }
    }
}

extern "C" void kernel_launch(void* const* d_in, const int* in_sizes, int n_in,
                              void* d_out, int out_size, void* d_ws, size_t ws_size,
                              hipStream_t stream) {
    const float* q  = (const float*)d_in[0];
    const float* k  = (const float*)d_in[1];
    const float* v  = (const float*)d_in[2];
    const float* Wq = (const float*)d_in[3];
    const float* Wk = (const float*)d_in[4];
    const float* Wv = (const float*)d_in[5];
    const float* Wo = (const float*)d_in[6];
    const float* bo = (const float*)d_in[7];
    unsigned short* ws = (unsigned short*)d_ws;  // 4x 65536 bf16 weights + 16384 f32 pos-enc

    prep_kernel<<<256, 256, 0, stream>>>(Wq, Wk, Wv, Wo, ws);
    attn_kernel<<<NVIEWS, 256, 0, stream>>>(q, k, v, ws, bo, (float*)d_out);
}

// Round 2
// 442.781 us; speedup vs baseline: 1.0165x; 1.0165x over previous
//
#include <hip/hip_runtime.h>
#include <math.h>

#define NVIEWS 1024
#define SS 64
#define DD 256

typedef __bf16 bf16x8 __attribute__((ext_vector_type(8)));
typedef float f32x4 __attribute__((ext_vector_type(4)));
typedef unsigned short us4 __attribute__((ext_vector_type(4)));

// LDS layout (bytes). Strides 16B-aligned; row shift = 4 banks -> worst 2-way (free, m136).
#define STR_W 264   // [64][256] bf16 buffers: row = 528B
#define STR_T 72    // [256][64] vpT and [64][64] P: row = 144B
#define OFF_A 0      // qp (33792) -> vpT (36864) -> gelu-out (33792)
#define OFF_B 36864  // kp (33792) -> attn-out (33792)
#define OFF_P 70656  // P (9216)
#define LDS_TOTAL 79872

__device__ __forceinline__ unsigned short f2bf(float f) {
    union { float f; unsigned int u; } x; x.f = f;
    return (unsigned short)((x.u + 0x7fffu + ((x.u >> 16) & 1u)) >> 16);
}
__device__ __forceinline__ float bf2f(unsigned short h) {
    union { unsigned int u; float f; } x; x.u = ((unsigned int)h) << 16;
    return x.f;
}

__global__ void prep_kernel(const float* __restrict__ Wq, const float* __restrict__ Wk,
                            const float* __restrict__ Wv, const float* __restrict__ Wo,
                            unsigned short* __restrict__ ws) {
    int idx = blockIdx.x * blockDim.x + threadIdx.x;  // 65536 threads
    if (idx < 65536) {
        ws[idx]          = f2bf(Wq[idx]);
        ws[idx + 65536]  = f2bf(Wk[idx]);
        ws[idx + 131072] = f2bf(Wv[idx]);
        ws[idx + 196608] = f2bf(Wo[idx]);
    }
    if (idx < SS * DD) {
        float* pe = (float*)(ws + 262144);
        int s = idx >> 8, j = idx & 255;
        float ang = (float)s * expf(-((float)(j >> 1)) * (9.210340371976184f / 128.0f));
        pe[idx] = (j & 1) ? cosf(ang) : sinf(ang);
    }
}

// 512 threads = 8 waves. Wave w: rows (w&1)*32 + {0,16}, cols (w>>1)*64 + {0,16,32,48}.
__global__ __launch_bounds__(512, 4)
void attn_kernel(const float* __restrict__ qg_, const float* __restrict__ kg_,
                 const float* __restrict__ vg_, const unsigned short* __restrict__ ws,
                 const float* __restrict__ bo, float* __restrict__ outg) {
    __shared__ __attribute__((aligned(16))) char smem[LDS_TOTAL];
    unsigned short* sA = (unsigned short*)(smem + OFF_A);  // qp -> vpT -> gelu-out
    unsigned short* sB = (unsigned short*)(smem + OFF_B);  // kp -> attn-out
    unsigned short* sP = (unsigned short*)(smem + OFF_P);

    const unsigned short* Wq = ws;
    const unsigned short* Wk = ws + 65536;
    const unsigned short* Wv = ws + 131072;
    const unsigned short* Wo = ws + 196608;
    const float* pe = (const float*)(ws + 262144);

    const int tid  = threadIdx.x;
    const int w    = tid >> 6;        // wave 0..7
    const int lane = tid & 63;
    const int quad = lane >> 4;
    const int l    = lane & 15;
    const int mrow0 = (w & 1) * 32;   // this wave's 32-row chunk
    const int ncol0 = (w >> 1) * 64;  // this wave's 64-col chunk
    const int koff = quad << 3;

    const size_t base = (size_t)blockIdx.x * (SS * DD);
    const float* qg = qg_ + base;
    const float* kg = kg_ + base;
    const float* vg = vg_ + base;
    float* og = outg + base;

    // acc[mt][nt] covers rows mrow0+mt*16, cols ncol0+nt*16
    auto project = [&](const float* __restrict__ X, const unsigned short* __restrict__ W,
                       f32x4 (&acc)[2][4]) {
        #pragma unroll 2
        for (int k0 = 0; k0 < DD; k0 += 32) {
            bf16x8 af[2], bfr[4];
            #pragma unroll
            for (int mt = 0; mt < 2; ++mt) {
                const float4* p = (const float4*)(X + (mrow0 + mt * 16 + l) * DD + k0 + koff);
                float4 a0 = p[0], a1 = p[1];
                union { unsigned short u[8]; bf16x8 v; } t;
                t.u[0] = f2bf(a0.x); t.u[1] = f2bf(a0.y); t.u[2] = f2bf(a0.z); t.u[3] = f2bf(a0.w);
                t.u[4] = f2bf(a1.x); t.u[5] = f2bf(a1.y); t.u[6] = f2bf(a1.z); t.u[7] = f2bf(a1.w);
                af[mt] = t.v;
            }
            #pragma unroll
            for (int nt = 0; nt < 4; ++nt)
                bfr[nt] = *(const bf16x8*)(W + (ncol0 + nt * 16 + l) * DD + k0 + koff);
            #pragma unroll
            for (int mt = 0; mt < 2; ++mt)
                #pragma unroll
                for (int nt = 0; nt < 4; ++nt)
                    acc[mt][nt] = __builtin_amdgcn_mfma_f32_16x16x32_bf16(af[mt], bfr[nt], acc[mt][nt], 0, 0, 0);
        }
    };
    auto zero = [](f32x4 (&acc)[2][4]) {
        #pragma unroll
        for (int i = 0; i < 2; ++i)
            #pragma unroll
            for (int j = 0; j < 4; ++j) acc[i][j] = (f32x4){0.f, 0.f, 0.f, 0.f};
    };
    // store C (+pe) as bf16 into dst[64][STR_W]
    auto store_pe = [&](f32x4 (&acc)[2][4], unsigned short* dst) {
        #pragma unroll
        for (int mt = 0; mt < 2; ++mt)
            #pragma unroll
            for (int nt = 0; nt < 4; ++nt) {
                int col = ncol0 + nt * 16 + l;
                #pragma unroll
                for (int r = 0; r < 4; ++r) {
                    int row = mrow0 + mt * 16 + (quad << 2) + r;
                    dst[row * STR_W + col] = f2bf(acc[mt][nt][r] + pe[row * DD + col]);
                }
            }
    };

    f32x4 acc[2][4];

    // ---- kp -> sB, qp -> sA ----
    zero(acc); project(kg, Wk, acc); store_pe(acc, sB);
    zero(acc); project(qg, Wq, acc); store_pe(acc, sA);
    __syncthreads();  // B1

    // ---- S = qp@kp^T + softmax: waves 0-3 (16 q-rows each); waves 4-7 go straight to proj-v ----
    if (w < 4) {
        f32x4 sacc[4];
        #pragma unroll
        for (int nt = 0; nt < 4; ++nt) sacc[nt] = (f32x4){0.f, 0.f, 0.f, 0.f};
        for (int k0 = 0; k0 < DD; k0 += 32) {
            bf16x8 a = *(const bf16x8*)(sA + (w * 16 + l) * STR_W + k0 + koff);
            #pragma unroll
            for (int nt = 0; nt < 4; ++nt) {
                bf16x8 b = *(const bf16x8*)(sB + (nt * 16 + l) * STR_W + k0 + koff);
                sacc[nt] = __builtin_amdgcn_mfma_f32_16x16x32_bf16(a, b, sacc[nt], 0, 0, 0);
            }
        }
        #pragma unroll
        for (int r = 0; r < 4; ++r) {
            float v0 = sacc[0][r] * 0.0625f, v1 = sacc[1][r] * 0.0625f;
            float v2 = sacc[2][r] * 0.0625f, v3 = sacc[3][r] * 0.0625f;
            float mx = fmaxf(fmaxf(v0, v1), fmaxf(v2, v3));
            #pragma unroll
            for (int d = 1; d <= 8; d <<= 1) mx = fmaxf(mx, __shfl_xor(mx, d));
            float e0 = __expf(v0 - mx), e1 = __expf(v1 - mx);
            float e2 = __expf(v2 - mx), e3 = __expf(v3 - mx);
            float sm = e0 + e1 + e2 + e3;
            #pragma unroll
            for (int d = 1; d <= 8; d <<= 1) sm += __shfl_xor(sm, d);
            float inv = 1.0f / sm;
            int row = w * 16 + (quad << 2) + r;
            sP[row * STR_T + l]      = f2bf(e0 * inv);
            sP[row * STR_T + 16 + l] = f2bf(e1 * inv);
            sP[row * STR_T + 32 + l] = f2bf(e2 * inv);
            sP[row * STR_T + 48 + l] = f2bf(e3 * inv);
        }
    }

    // ---- vp (registers only until B2), then transpose-write vpT into sA ----
    zero(acc);
    project(vg, Wv, acc);
    __syncthreads();  // B2: all sA/sB reads of phase S done; sP complete
    #pragma unroll
    for (int mt = 0; mt < 2; ++mt)
        #pragma unroll
        for (int nt = 0; nt < 4; ++nt) {
            int col = ncol0 + nt * 16 + l;           // d index = vpT row
            int rbase = mrow0 + mt * 16 + (quad << 2);
            us4 pk;
            #pragma unroll
            for (int r = 0; r < 4; ++r)
                pk[r] = f2bf(acc[mt][nt][r] + pe[(rbase + r) * DD + col]);
            *(us4*)(sA + col * STR_T + rbase) = pk;  // 8B transpose write
        }
    __syncthreads();  // B3: vpT visible

    // ---- attn-out = P @ vp -> sB ----
    {
        f32x4 oacc[2][4];
        zero(oacc);
        #pragma unroll
        for (int k0 = 0; k0 < 64; k0 += 32) {
            bf16x8 af[2], bfr[4];
            #pragma unroll
            for (int mt = 0; mt < 2; ++mt)
                af[mt] = *(const bf16x8*)(sP + (mrow0 + mt * 16 + l) * STR_T + k0 + koff);
            #pragma unroll
            for (int nt = 0; nt < 4; ++nt)
                bfr[nt] = *(const bf16x8*)(sA + (ncol0 + nt * 16 + l) * STR_T + k0 + koff);
            #pragma unroll
            for (int mt = 0; mt < 2; ++mt)
                #pragma unroll
                for (int nt = 0; nt < 4; ++nt)
                    oacc[mt][nt] = __builtin_amdgcn_mfma_f32_16x16x32_bf16(af[mt], bfr[nt], oacc[mt][nt], 0, 0, 0);
        }
        #pragma unroll
        for (int mt = 0; mt < 2; ++mt)
            #pragma unroll
            for (int nt = 0; nt < 4; ++nt) {
                int col = ncol0 + nt * 16 + l;
                #pragma unroll
                for (int r = 0; r < 4; ++r)
                    sB[(mrow0 + mt * 16 + (quad << 2) + r) * STR_W + col] = f2bf(oacc[mt][nt][r]);
            }
    }
    __syncthreads();  // B4: attn-out visible (also: vpT reads done)

    // ---- y' = gelu(attn-out @ Wo^T + bo) -> sA (bf16), then coalesced epilogue ----
    {
        f32x4 facc[2][4];
        zero(facc);
        #pragma unroll 2
        for (int k0 = 0; k0 < DD; k0 += 32) {
            bf16x8 af[2], bfr[4];
            #pragma unroll
            for (int mt = 0; mt < 2; ++mt)
                af[mt] = *(const bf16x8*)(sB + (mrow0 + mt * 16 + l) * STR_W + k0 + koff);
            #pragma unroll
            for (int nt = 0; nt < 4; ++nt)
                bfr[nt] = *(const bf16x8*)(Wo + (ncol0 + nt * 16 + l) * DD + k0 + koff);
            #pragma unroll
            for (int mt = 0; mt < 2; ++mt)
                #pragma unroll
                for (int nt = 0; nt < 4; ++nt)
                    facc[mt][nt] = __builtin_amdgcn_mfma_f32_16x16x32_bf16(af[mt], bfr[nt], facc[mt][nt], 0, 0, 0);
        }
        #pragma unroll
        for (int nt = 0; nt < 4; ++nt) {
            float bias = bo[ncol0 + nt * 16 + l];
            #pragma unroll
            for (int mt = 0; mt < 2; ++mt) {
                int col = ncol0 + nt * 16 + l;
                #pragma unroll
                for (int r = 0; r < 4; ++r) {
                    int row = mrow0 + mt * 16 + (quad << 2) + r;
                    float y = facc[mt][nt][r] + bias;
                    float g = 0.5f * y * (1.0f + erff(y * 0.7071067811865475f));
                    sA[row * STR_W + col] = f2bf(g);
                }
            }
        }
    }
    __syncthreads();  // B5: gelu-out visible

    // ---- coalesced: out = gelu-out + q (residual), float4 stores ----
    #pragma unroll
    for (int s = 0; s < 8; ++s) {
        int f = s * 2048 + tid * 4;        // flat fp32 index, lane-consecutive
        int row = f >> 8, col = f & 255;
        us4 gb = *(const us4*)(sA + row * STR_W + col);
        float4 qv = *(const float4*)(qg + f);
        float4 o;
        o.x = bf2f(gb[0]) + qv.x;
        o.y = bf2f(gb[1]) + qv.y;
        o.z = bf2f(gb[2]) + qv.z;
        o.w = bf2f(gb[3]) + qv.w;
        *(float4*)(og + f) = o;
    }
}

extern "C" void kernel_launch(void* const* d_in, const int* in_sizes, int n_in,
                              void* d_out, int out_size, void* d_ws, size_t ws_size,
                              hipStream_t stream) {
    const float* q  = (const float*)d_in[0];
    const float* k  = (const float*)d_in[1];
    const float* v  = (const float*)d_in[2];
    const float* Wq = (const float*)d_in[3];
    const float* Wk = (const float*)d_in[4];
    const float* Wv = (const float*)d_in[5];
    const float* Wo = (const float*)d_in[6];
    const float* bo = (const float*)d_in[7];
    unsigned short* ws = (unsigned short*)d_ws;  // 4x 65536 bf16 weights + 16384 f32 pos-enc

    prep_kernel<<<256, 256, 0, stream>>>(Wq, Wk, Wv, Wo, ws);
    attn_kernel<<<NVIEWS, 512, 0, stream>>>(q, k, v, ws, bo, (float*)d_out);
}

// Round 3
// 426.307 us; speedup vs baseline: 1.0558x; 1.0386x over previous
//
#include <hip/hip_runtime.h>
#include <math.h>

#define NVIEWS 1024
#define SS 64
#define DD 256

typedef __bf16 bf16x8 __attribute__((ext_vector_type(8)));
typedef float f32x4 __attribute__((ext_vector_type(4)));
typedef unsigned short us4 __attribute__((ext_vector_type(4)));
typedef unsigned short us8 __attribute__((ext_vector_type(8)));

// LDS layout (bytes). Strides 16B-aligned; row shift = 4 banks -> worst 2-way (free).
#define STR_W 264   // [64][256] bf16 buffers: row = 528B
#define STR_T 72    // [256][64] vpT and [64][64] P: row = 144B
#define OFF_A 0      // qp (33792) -> vpT (36864) -> gelu-out (33792)
#define OFF_B 36864  // kp (33792) -> attn-out (33792)
#define OFF_P 70656  // P (9216)
#define LDS_TOTAL 79872

__device__ __forceinline__ unsigned short f2bf(float f) {
    unsigned int u = __builtin_bit_cast(unsigned int, f);
    return (unsigned short)((u + 0x7fffu + ((u >> 16) & 1u)) >> 16);
}
__device__ __forceinline__ float bf2f(unsigned short h) {
    unsigned int u = ((unsigned int)h) << 16;
    return __builtin_bit_cast(float, u);
}

__global__ void prep_kernel(const float* __restrict__ Wq, const float* __restrict__ Wk,
                            const float* __restrict__ Wv, const float* __restrict__ Wo,
                            unsigned short* __restrict__ ws) {
    int t = blockIdx.x * blockDim.x + threadIdx.x;  // 16384 threads, 4 elems each
    int i4 = t * 4;
    {
        float4 a = *(const float4*)(Wq + i4);
        us4 o; o[0] = f2bf(a.x); o[1] = f2bf(a.y); o[2] = f2bf(a.z); o[3] = f2bf(a.w);
        *(us4*)(ws + i4) = o;
    }
    {
        float4 a = *(const float4*)(Wk + i4);
        us4 o; o[0] = f2bf(a.x); o[1] = f2bf(a.y); o[2] = f2bf(a.z); o[3] = f2bf(a.w);
        *(us4*)(ws + 65536 + i4) = o;
    }
    {
        float4 a = *(const float4*)(Wv + i4);
        us4 o; o[0] = f2bf(a.x); o[1] = f2bf(a.y); o[2] = f2bf(a.z); o[3] = f2bf(a.w);
        *(us4*)(ws + 131072 + i4) = o;
    }
    {
        float4 a = *(const float4*)(Wo + i4);
        us4 o; o[0] = f2bf(a.x); o[1] = f2bf(a.y); o[2] = f2bf(a.z); o[3] = f2bf(a.w);
        *(us4*)(ws + 196608 + i4) = o;
    }
    if (t < 4096) {  // pos-enc table, 16384 floats
        float* pe = (float*)(ws + 262144);
        int s = i4 >> 8, j = i4 & 255;  // j even, i4%4==0
        float a0 = (float)s * expf(-((float)(j >> 1))       * (9.210340371976184f / 128.0f));
        float a1 = (float)s * expf(-((float)((j + 2) >> 1)) * (9.210340371976184f / 128.0f));
        float4 o; o.x = sinf(a0); o.y = cosf(a0); o.z = sinf(a1); o.w = cosf(a1);
        *(float4*)(pe + i4) = o;
    }
}

// One A-fragment: 8 consecutive fp32 -> bf16x8 (built via constant-index inserts, SSA-safe)
#define LOAD_A_FRAG(dst, Xp, row, kk)                                          \
    {                                                                          \
        const float4* _p = (const float4*)((Xp) + (row) * DD + (kk));          \
        float4 _a0 = _p[0], _a1 = _p[1];                                       \
        us8 _t;                                                                \
        _t[0] = f2bf(_a0.x); _t[1] = f2bf(_a0.y); _t[2] = f2bf(_a0.z); _t[3] = f2bf(_a0.w); \
        _t[4] = f2bf(_a1.x); _t[5] = f2bf(_a1.y); _t[6] = f2bf(_a1.z); _t[7] = f2bf(_a1.w); \
        dst = _t;                                                              \
    }

#define MFMA(d, a, b) d = __builtin_amdgcn_mfma_f32_16x16x32_bf16(             \
        __builtin_bit_cast(bf16x8, a), __builtin_bit_cast(bf16x8, b), d, 0, 0, 0)

// Full projection: acc[2][4] covers rows mrow0+{0,16}+.., cols ncol0+{0..63}
#define PROJECT(Xp, Wp)                                                        \
    _Pragma("unroll 2")                                                        \
    for (int k0 = 0; k0 < DD; k0 += 32) {                                      \
        us8 af0, af1, bf0, bf1, bf2, bf3;                                      \
        LOAD_A_FRAG(af0, Xp, mrow0 + l, k0 + koff);                            \
        LOAD_A_FRAG(af1, Xp, mrow0 + 16 + l, k0 + koff);                       \
        bf0 = *(const us8*)((Wp) + (ncol0 + l) * DD + k0 + koff);              \
        bf1 = *(const us8*)((Wp) + (ncol0 + 16 + l) * DD + k0 + koff);         \
        bf2 = *(const us8*)((Wp) + (ncol0 + 32 + l) * DD + k0 + koff);         \
        bf3 = *(const us8*)((Wp) + (ncol0 + 48 + l) * DD + k0 + koff);         \
        MFMA(acc[0][0], af0, bf0); MFMA(acc[0][1], af0, bf1);                  \
        MFMA(acc[0][2], af0, bf2); MFMA(acc[0][3], af0, bf3);                  \
        MFMA(acc[1][0], af1, bf0); MFMA(acc[1][1], af1, bf1);                  \
        MFMA(acc[1][2], af1, bf2); MFMA(acc[1][3], af1, bf3);                  \
    }

#define ZERO_ACC                                                               \
    _Pragma("unroll")                                                          \
    for (int _i = 0; _i < 2; ++_i)                                             \
        _Pragma("unroll")                                                      \
        for (int _j = 0; _j < 4; ++_j) acc[_i][_j] = (f32x4){0.f, 0.f, 0.f, 0.f};

// Store acc (+pe) as bf16 into dst[64][STR_W]
#define STORE_PE(dst)                                                          \
    _Pragma("unroll")                                                          \
    for (int mt = 0; mt < 2; ++mt)                                             \
        _Pragma("unroll")                                                      \
        for (int nt = 0; nt < 4; ++nt) {                                       \
            int col = ncol0 + nt * 16 + l;                                     \
            _Pragma("unroll")                                                  \
            for (int r = 0; r < 4; ++r) {                                      \
                int row = mrow0 + mt * 16 + (quad << 2) + r;                   \
                (dst)[row * STR_W + col] = f2bf(acc[mt][nt][r] + pe[row * DD + col]); \
            }                                                                  \
        }

// 512 threads = 8 waves. Wave w: rows (w&1)*32 + {0,16}, cols (w>>1)*64 + {0,16,32,48}.
__global__ __launch_bounds__(512, 4)
void attn_kernel(const float* __restrict__ qg_, const float* __restrict__ kg_,
                 const float* __restrict__ vg_, const unsigned short* __restrict__ ws,
                 const float* __restrict__ bo, float* __restrict__ outg) {
    __shared__ __attribute__((aligned(16))) char smem[LDS_TOTAL];
    unsigned short* sA = (unsigned short*)(smem + OFF_A);  // qp -> vpT -> gelu-out
    unsigned short* sB = (unsigned short*)(smem + OFF_B);  // kp -> attn-out
    unsigned short* sP = (unsigned short*)(smem + OFF_P);

    const unsigned short* Wq = ws;
    const unsigned short* Wk = ws + 65536;
    const unsigned short* Wv = ws + 131072;
    const unsigned short* Wo = ws + 196608;
    const float* pe = (const float*)(ws + 262144);

    const int tid  = threadIdx.x;
    const int w    = tid >> 6;
    const int lane = tid & 63;
    const int quad = lane >> 4;
    const int l    = lane & 15;
    const int mrow0 = (w & 1) * 32;
    const int ncol0 = (w >> 1) * 64;
    const int koff = quad << 3;

    const size_t base = (size_t)blockIdx.x * (SS * DD);
    const float* qg = qg_ + base;
    const float* kg = kg_ + base;
    const float* vg = vg_ + base;
    float* og = outg + base;

    f32x4 acc[2][4];

    // ---- kp = k@Wk^T + pe -> sB ----
    ZERO_ACC
    PROJECT(kg, Wk)
    STORE_PE(sB)

    // ---- qp = q@Wq^T + pe -> sA ----
    ZERO_ACC
    PROJECT(qg, Wq)
    STORE_PE(sA)

    __syncthreads();  // B1

    // ---- S = qp@kp^T + softmax: waves 0-3 (16 q-rows each) ----
    if (w < 4) {
        f32x4 s0 = {0.f,0.f,0.f,0.f}, s1 = {0.f,0.f,0.f,0.f};
        f32x4 s2 = {0.f,0.f,0.f,0.f}, s3 = {0.f,0.f,0.f,0.f};
        #pragma unroll
        for (int k0 = 0; k0 < DD; k0 += 32) {
            us8 a = *(const us8*)(sA + (w * 16 + l) * STR_W + k0 + koff);
            us8 b0 = *(const us8*)(sB + (l) * STR_W + k0 + koff);
            us8 b1 = *(const us8*)(sB + (16 + l) * STR_W + k0 + koff);
            us8 b2 = *(const us8*)(sB + (32 + l) * STR_W + k0 + koff);
            us8 b3 = *(const us8*)(sB + (48 + l) * STR_W + k0 + koff);
            MFMA(s0, a, b0); MFMA(s1, a, b1); MFMA(s2, a, b2); MFMA(s3, a, b3);
        }
        #pragma unroll
        for (int r = 0; r < 4; ++r) {
            float v0 = s0[r] * 0.0625f, v1 = s1[r] * 0.0625f;
            float v2 = s2[r] * 0.0625f, v3 = s3[r] * 0.0625f;
            float mx = fmaxf(fmaxf(v0, v1), fmaxf(v2, v3));
            #pragma unroll
            for (int d = 1; d <= 8; d <<= 1) mx = fmaxf(mx, __shfl_xor(mx, d));
            float e0 = __expf(v0 - mx), e1 = __expf(v1 - mx);
            float e2 = __expf(v2 - mx), e3 = __expf(v3 - mx);
            float sm = e0 + e1 + e2 + e3;
            #pragma unroll
            for (int d = 1; d <= 8; d <<= 1) sm += __shfl_xor(sm, d);
            float inv = 1.0f / sm;
            int row = w * 16 + (quad << 2) + r;
            sP[row * STR_T + l]      = f2bf(e0 * inv);
            sP[row * STR_T + 16 + l] = f2bf(e1 * inv);
            sP[row * STR_T + 32 + l] = f2bf(e2 * inv);
            sP[row * STR_T + 48 + l] = f2bf(e3 * inv);
        }
    }

    // ---- vp = v@Wv^T (registers only until B2) ----
    ZERO_ACC
    PROJECT(vg, Wv)
    __syncthreads();  // B2: S-phase LDS reads done; sP complete
    // transpose-write vpT (+pe) into sA [256][STR_T]
    #pragma unroll
    for (int mt = 0; mt < 2; ++mt)
        #pragma unroll
        for (int nt = 0; nt < 4; ++nt) {
            int col = ncol0 + nt * 16 + l;            // d index = vpT row
            int rbase = mrow0 + mt * 16 + (quad << 2);
            us4 pk;
            #pragma unroll
            for (int r = 0; r < 4; ++r)
                pk[r] = f2bf(acc[mt][nt][r] + pe[(rbase + r) * DD + col]);
            *(us4*)(sA + col * STR_T + rbase) = pk;   // 8B transpose write
        }
    __syncthreads();  // B3: vpT visible

    // ---- attn-out = P @ vp -> sB ----
    {
        ZERO_ACC
        #pragma unroll
        for (int k0 = 0; k0 < 64; k0 += 32) {
            us8 a0 = *(const us8*)(sP + (mrow0 + l) * STR_T + k0 + koff);
            us8 a1 = *(const us8*)(sP + (mrow0 + 16 + l) * STR_T + k0 + koff);
            us8 b0 = *(const us8*)(sA + (ncol0 + l) * STR_T + k0 + koff);
            us8 b1 = *(const us8*)(sA + (ncol0 + 16 + l) * STR_T + k0 + koff);
            us8 b2 = *(const us8*)(sA + (ncol0 + 32 + l) * STR_T + k0 + koff);
            us8 b3 = *(const us8*)(sA + (ncol0 + 48 + l) * STR_T + k0 + koff);
            MFMA(acc[0][0], a0, b0); MFMA(acc[0][1], a0, b1);
            MFMA(acc[0][2], a0, b2); MFMA(acc[0][3], a0, b3);
            MFMA(acc[1][0], a1, b0); MFMA(acc[1][1], a1, b1);
            MFMA(acc[1][2], a1, b2); MFMA(acc[1][3], a1, b3);
        }
        #pragma unroll
        for (int mt = 0; mt < 2; ++mt)
            #pragma unroll
            for (int nt = 0; nt < 4; ++nt) {
                int col = ncol0 + nt * 16 + l;
                #pragma unroll
                for (int r = 0; r < 4; ++r)
                    sB[(mrow0 + mt * 16 + (quad << 2) + r) * STR_W + col] = f2bf(acc[mt][nt][r]);
            }
    }
    __syncthreads();  // B4: attn-out visible; vpT reads done

    // ---- y' = gelu(attn-out @ Wo^T + bo) -> sA ----
    {
        ZERO_ACC
        #pragma unroll 2
        for (int k0 = 0; k0 < DD; k0 += 32) {
            us8 a0 = *(const us8*)(sB + (mrow0 + l) * STR_W + k0 + koff);
            us8 a1 = *(const us8*)(sB + (mrow0 + 16 + l) * STR_W + k0 + koff);
            us8 b0 = *(const us8*)(Wo + (ncol0 + l) * DD + k0 + koff);
            us8 b1 = *(const us8*)(Wo + (ncol0 + 16 + l) * DD + k0 + koff);
            us8 b2 = *(const us8*)(Wo + (ncol0 + 32 + l) * DD + k0 + koff);
            us8 b3 = *(const us8*)(Wo + (ncol0 + 48 + l) * DD + k0 + koff);
            MFMA(acc[0][0], a0, b0); MFMA(acc[0][1], a0, b1);
            MFMA(acc[0][2], a0, b2); MFMA(acc[0][3], a0, b3);
            MFMA(acc[1][0], a1, b0); MFMA(acc[1][1], a1, b1);
            MFMA(acc[1][2], a1, b2); MFMA(acc[1][3], a1, b3);
        }
        #pragma unroll
        for (int nt = 0; nt < 4; ++nt) {
            int col = ncol0 + nt * 16 + l;
            float bias = bo[col];
            #pragma unroll
            for (int mt = 0; mt < 2; ++mt) {
                #pragma unroll
                for (int r = 0; r < 4; ++r) {
                    int row = mrow0 + mt * 16 + (quad << 2) + r;
                    float y = acc[mt][nt][r] + bias;
                    float g = 0.5f * y * (1.0f + erff(y * 0.7071067811865475f));
                    sA[row * STR_W + col] = f2bf(g);
                }
            }
        }
    }
    __syncthreads();  // B5: gelu-out visible

    // ---- coalesced epilogue: out = gelu-out + q ----
    #pragma unroll
    for (int s = 0; s < 8; ++s) {
        int f = s * 2048 + tid * 4;
        int row = f >> 8, col = f & 255;
        us4 gb = *(const us4*)(sA + row * STR_W + col);
        float4 qv = *(const float4*)(qg + f);
        float4 o;
        o.x = bf2f(gb[0]) + qv.x;
        o.y = bf2f(gb[1]) + qv.y;
        o.z = bf2f(gb[2]) + qv.z;
        o.w = bf2f(gb[3]) + qv.w;
        *(float4*)(og + f) = o;
    }
}

extern "C" void kernel_launch(void* const* d_in, const int* in_sizes, int n_in,
                              void* d_out, int out_size, void* d_ws, size_t ws_size,
                              hipStream_t stream) {
    const float* q  = (const float*)d_in[0];
    const float* k  = (const float*)d_in[1];
    const float* v  = (const float*)d_in[2];
    const float* Wq = (const float*)d_in[3];
    const float* Wk = (const float*)d_in[4];
    const float* Wv = (const float*)d_in[5];
    const float* Wo = (const float*)d_in[6];
    const float* bo = (const float*)d_in[7];
    unsigned short* ws = (unsigned short*)d_ws;  // 4x 65536 bf16 weights + 16384 f32 pos-enc

    prep_kernel<<<64, 256, 0, stream>>>(Wq, Wk, Wv, Wo, ws);
    attn_kernel<<<NVIEWS, 512, 0, stream>>>(q, k, v, ws, bo, (float*)d_out);
}

// Round 4
// 373.975 us; speedup vs baseline: 1.2035x; 1.1399x over previous
//
#include <hip/hip_runtime.h>
#include <math.h>

#define NVIEWS 1024
#define SS 64
#define DD 256

typedef __bf16 bf16x8 __attribute__((ext_vector_type(8)));
typedef float f32x4 __attribute__((ext_vector_type(4)));
typedef unsigned short us4 __attribute__((ext_vector_type(4)));
typedef unsigned short us8 __attribute__((ext_vector_type(8)));
typedef unsigned int u32x4 __attribute__((ext_vector_type(4)));

// LDS layout (bytes). Strides 16B-aligned; row shift = 4 banks -> worst 2-way (free).
#define STR_W 264   // [64][256] bf16 buffers: row = 528B
#define STR_T 72    // [256][64] vpT and [64][64] P: row = 144B
#define OFF_A 0      // qp (33792) -> vpT (36864) -> gelu-out (33792)
#define OFF_B 36864  // kp (33792) -> attn-out (33792)
#define OFF_P 70656  // P (9216)
#define LDS_TOTAL 79872

// round-half-up f32->bf16: 2 VALU (vs 4 for RNE); tie-only deviation, irrelevant at our margin
__device__ __forceinline__ unsigned short f2bf(float f) {
    return (unsigned short)((__builtin_bit_cast(unsigned int, f) + 0x8000u) >> 16);
}
__device__ __forceinline__ float bf2f(unsigned short h) {
    unsigned int u = ((unsigned int)h) << 16;
    return __builtin_bit_cast(float, u);
}
// pack two rounded f32 into one dword of 2 bf16 via v_perm_b32
__device__ __forceinline__ unsigned int packbf2(float lo, float hi) {
    unsigned int ul = __builtin_bit_cast(unsigned int, lo) + 0x8000u;
    unsigned int uh = __builtin_bit_cast(unsigned int, hi) + 0x8000u;
    return __builtin_amdgcn_perm(uh, ul, 0x07060302u);
}

__global__ void prep_kernel(const float* __restrict__ Wq, const float* __restrict__ Wk,
                            const float* __restrict__ Wv, const float* __restrict__ Wo,
                            unsigned short* __restrict__ ws) {
    int t = blockIdx.x * blockDim.x + threadIdx.x;  // 16384 threads, 4 elems each
    int i4 = t * 4;
    {
        float4 a = *(const float4*)(Wq + i4);
        us4 o; o[0] = f2bf(a.x); o[1] = f2bf(a.y); o[2] = f2bf(a.z); o[3] = f2bf(a.w);
        *(us4*)(ws + i4) = o;
    }
    {
        float4 a = *(const float4*)(Wk + i4);
        us4 o; o[0] = f2bf(a.x); o[1] = f2bf(a.y); o[2] = f2bf(a.z); o[3] = f2bf(a.w);
        *(us4*)(ws + 65536 + i4) = o;
    }
    {
        float4 a = *(const float4*)(Wv + i4);
        us4 o; o[0] = f2bf(a.x); o[1] = f2bf(a.y); o[2] = f2bf(a.z); o[3] = f2bf(a.w);
        *(us4*)(ws + 131072 + i4) = o;
    }
    {
        float4 a = *(const float4*)(Wo + i4);
        us4 o; o[0] = f2bf(a.x); o[1] = f2bf(a.y); o[2] = f2bf(a.z); o[3] = f2bf(a.w);
        *(us4*)(ws + 196608 + i4) = o;
    }
    if (t < 4096) {  // pos-enc table, 16384 floats
        float* pe = (float*)(ws + 262144);
        int s = i4 >> 8, j = i4 & 255;
        float a0 = (float)s * expf(-((float)(j >> 1))       * (9.210340371976184f / 128.0f));
        float a1 = (float)s * expf(-((float)((j + 2) >> 1)) * (9.210340371976184f / 128.0f));
        float4 o; o.x = sinf(a0); o.y = cosf(a0); o.z = sinf(a1); o.w = cosf(a1);
        *(float4*)(pe + i4) = o;
    }
}

// A-fragment: 8 consecutive fp32 -> bf16x8 via 2 float4 loads + 4 v_perm packs
#define LOAD_A_FRAG(dst, Xp, row, kk)                                          \
    {                                                                          \
        const float4* _p = (const float4*)((Xp) + (row) * DD + (kk));          \
        float4 _a = _p[0], _b = _p[1];                                         \
        u32x4 _w;                                                              \
        _w[0] = packbf2(_a.x, _a.y); _w[1] = packbf2(_a.z, _a.w);              \
        _w[2] = packbf2(_b.x, _b.y); _w[3] = packbf2(_b.z, _b.w);              \
        dst = __builtin_bit_cast(us8, _w);                                     \
    }

#define MFMA(d, a, b) d = __builtin_amdgcn_mfma_f32_16x16x32_bf16(             \
        __builtin_bit_cast(bf16x8, a), __builtin_bit_cast(bf16x8, b), d, 0, 0, 0)

// acc[4][4]: rows mt*16+.., cols n0+nt*16+..  (wave covers all 64 rows x its 64 cols)
#define PROJECT(Xp, Wp)                                                        \
    _Pragma("unroll 2")                                                        \
    for (int k0 = 0; k0 < DD; k0 += 32) {                                      \
        us8 af0, af1, af2, af3, bq0, bq1, bq2, bq3;                            \
        LOAD_A_FRAG(af0, Xp, l, k0 + koff);                                    \
        LOAD_A_FRAG(af1, Xp, 16 + l, k0 + koff);                               \
        LOAD_A_FRAG(af2, Xp, 32 + l, k0 + koff);                               \
        LOAD_A_FRAG(af3, Xp, 48 + l, k0 + koff);                               \
        bq0 = *(const us8*)((Wp) + (n0 + l) * DD + k0 + koff);                 \
        bq1 = *(const us8*)((Wp) + (n0 + 16 + l) * DD + k0 + koff);            \
        bq2 = *(const us8*)((Wp) + (n0 + 32 + l) * DD + k0 + koff);            \
        bq3 = *(const us8*)((Wp) + (n0 + 48 + l) * DD + k0 + koff);            \
        MFMA(acc[0][0], af0, bq0); MFMA(acc[0][1], af0, bq1);                  \
        MFMA(acc[0][2], af0, bq2); MFMA(acc[0][3], af0, bq3);                  \
        MFMA(acc[1][0], af1, bq0); MFMA(acc[1][1], af1, bq1);                  \
        MFMA(acc[1][2], af1, bq2); MFMA(acc[1][3], af1, bq3);                  \
        MFMA(acc[2][0], af2, bq0); MFMA(acc[2][1], af2, bq1);                  \
        MFMA(acc[2][2], af2, bq2); MFMA(acc[2][3], af2, bq3);                  \
        MFMA(acc[3][0], af3, bq0); MFMA(acc[3][1], af3, bq1);                  \
        MFMA(acc[3][2], af3, bq2); MFMA(acc[3][3], af3, bq3);                  \
    }

#define ZERO_ACC                                                               \
    _Pragma("unroll")                                                          \
    for (int _i = 0; _i < 4; ++_i)                                             \
        _Pragma("unroll")                                                      \
        for (int _j = 0; _j < 4; ++_j) acc[_i][_j] = (f32x4){0.f, 0.f, 0.f, 0.f};

// Store acc (+pe) as bf16 into dst[64][STR_W]
#define STORE_PE(dst)                                                          \
    _Pragma("unroll")                                                          \
    for (int mt = 0; mt < 4; ++mt)                                             \
        _Pragma("unroll")                                                      \
        for (int nt = 0; nt < 4; ++nt) {                                       \
            int col = n0 + nt * 16 + l;                                        \
            _Pragma("unroll")                                                  \
            for (int r = 0; r < 4; ++r) {                                      \
                int row = mt * 16 + (quad << 2) + r;                           \
                (dst)[row * STR_W + col] = f2bf(acc[mt][nt][r] + pe[row * DD + col]); \
            }                                                                  \
        }

// 256 threads = 4 waves. Wave w: all 64 rows, cols w*64..w*64+63.
__global__ __launch_bounds__(256, 2)
void attn_kernel(const float* __restrict__ qg_, const float* __restrict__ kg_,
                 const float* __restrict__ vg_, const unsigned short* __restrict__ ws,
                 const float* __restrict__ bo, float* __restrict__ outg) {
    __shared__ __attribute__((aligned(16))) char smem[LDS_TOTAL];
    unsigned short* sA = (unsigned short*)(smem + OFF_A);  // qp -> vpT -> gelu-out
    unsigned short* sB = (unsigned short*)(smem + OFF_B);  // kp -> attn-out
    unsigned short* sP = (unsigned short*)(smem + OFF_P);

    const unsigned short* Wq = ws;
    const unsigned short* Wk = ws + 65536;
    const unsigned short* Wv = ws + 131072;
    const unsigned short* Wo = ws + 196608;
    const float* pe = (const float*)(ws + 262144);

    const int tid  = threadIdx.x;
    const int w    = tid >> 6;        // wave 0..3
    const int lane = tid & 63;
    const int quad = lane >> 4;
    const int l    = lane & 15;
    const int n0   = w << 6;          // this wave's 64-col chunk
    const int koff = quad << 3;

    const size_t base = (size_t)blockIdx.x * (SS * DD);
    const float* qg = qg_ + base;
    const float* kg = kg_ + base;
    const float* vg = vg_ + base;
    float* og = outg + base;

    f32x4 acc[4][4];

    // ---- kp = k@Wk^T + pe -> sB ----
    ZERO_ACC
    PROJECT(kg, Wk)
    STORE_PE(sB)

    // ---- qp = q@Wq^T + pe -> sA ----
    ZERO_ACC
    PROJECT(qg, Wq)
    STORE_PE(sA)

    __syncthreads();  // B1

    // ---- S = qp@kp^T + softmax: wave w owns q-rows w*16..w*16+15 ----
    {
        f32x4 s0 = {0.f,0.f,0.f,0.f}, s1 = {0.f,0.f,0.f,0.f};
        f32x4 s2 = {0.f,0.f,0.f,0.f}, s3 = {0.f,0.f,0.f,0.f};
        #pragma unroll
        for (int k0 = 0; k0 < DD; k0 += 32) {
            us8 a  = *(const us8*)(sA + (w * 16 + l) * STR_W + k0 + koff);
            us8 b0 = *(const us8*)(sB + (l) * STR_W + k0 + koff);
            us8 b1 = *(const us8*)(sB + (16 + l) * STR_W + k0 + koff);
            us8 b2 = *(const us8*)(sB + (32 + l) * STR_W + k0 + koff);
            us8 b3 = *(const us8*)(sB + (48 + l) * STR_W + k0 + koff);
            MFMA(s0, a, b0); MFMA(s1, a, b1); MFMA(s2, a, b2); MFMA(s3, a, b3);
        }
        #pragma unroll
        for (int r = 0; r < 4; ++r) {
            float v0 = s0[r] * 0.0625f, v1 = s1[r] * 0.0625f;
            float v2 = s2[r] * 0.0625f, v3 = s3[r] * 0.0625f;
            float mx = fmaxf(fmaxf(v0, v1), fmaxf(v2, v3));
            #pragma unroll
            for (int d = 1; d <= 8; d <<= 1) mx = fmaxf(mx, __shfl_xor(mx, d));
            float e0 = __expf(v0 - mx), e1 = __expf(v1 - mx);
            float e2 = __expf(v2 - mx), e3 = __expf(v3 - mx);
            float sm = e0 + e1 + e2 + e3;
            #pragma unroll
            for (int d = 1; d <= 8; d <<= 1) sm += __shfl_xor(sm, d);
            float inv = 1.0f / sm;
            int row = w * 16 + (quad << 2) + r;
            sP[row * STR_T + l]      = f2bf(e0 * inv);
            sP[row * STR_T + 16 + l] = f2bf(e1 * inv);
            sP[row * STR_T + 32 + l] = f2bf(e2 * inv);
            sP[row * STR_T + 48 + l] = f2bf(e3 * inv);
        }
    }

    // ---- vp = v@Wv^T (registers only until B2) ----
    ZERO_ACC
    PROJECT(vg, Wv)
    __syncthreads();  // B2: S-phase LDS reads done; sP complete
    // transpose-write vpT (+pe) into sA [256][STR_T]
    #pragma unroll
    for (int mt = 0; mt < 4; ++mt)
        #pragma unroll
        for (int nt = 0; nt < 4; ++nt) {
            int col = n0 + nt * 16 + l;            // d index = vpT row
            int rbase = mt * 16 + (quad << 2);
            us4 pk;
            #pragma unroll
            for (int r = 0; r < 4; ++r)
                pk[r] = f2bf(acc[mt][nt][r] + pe[(rbase + r) * DD + col]);
            *(us4*)(sA + col * STR_T + rbase) = pk;   // 8B transpose write
        }
    __syncthreads();  // B3: vpT visible

    // ---- attn-out = P @ vp -> sB ----
    {
        ZERO_ACC
        #pragma unroll
        for (int k0 = 0; k0 < 64; k0 += 32) {
            us8 a0 = *(const us8*)(sP + (l) * STR_T + k0 + koff);
            us8 a1 = *(const us8*)(sP + (16 + l) * STR_T + k0 + koff);
            us8 a2 = *(const us8*)(sP + (32 + l) * STR_T + k0 + koff);
            us8 a3 = *(const us8*)(sP + (48 + l) * STR_T + k0 + koff);
            us8 b0 = *(const us8*)(sA + (n0 + l) * STR_T + k0 + koff);
            us8 b1 = *(const us8*)(sA + (n0 + 16 + l) * STR_T + k0 + koff);
            us8 b2 = *(const us8*)(sA + (n0 + 32 + l) * STR_T + k0 + koff);
            us8 b3 = *(const us8*)(sA + (n0 + 48 + l) * STR_T + k0 + koff);
            MFMA(acc[0][0], a0, b0); MFMA(acc[0][1], a0, b1);
            MFMA(acc[0][2], a0, b2); MFMA(acc[0][3], a0, b3);
            MFMA(acc[1][0], a1, b0); MFMA(acc[1][1], a1, b1);
            MFMA(acc[1][2], a1, b2); MFMA(acc[1][3], a1, b3);
            MFMA(acc[2][0], a2, b0); MFMA(acc[2][1], a2, b1);
            MFMA(acc[2][2], a2, b2); MFMA(acc[2][3], a2, b3);
            MFMA(acc[3][0], a3, b0); MFMA(acc[3][1], a3, b1);
            MFMA(acc[3][2], a3, b2); MFMA(acc[3][3], a3, b3);
        }
        #pragma unroll
        for (int mt = 0; mt < 4; ++mt)
            #pragma unroll
            for (int nt = 0; nt < 4; ++nt) {
                int col = n0 + nt * 16 + l;
                #pragma unroll
                for (int r = 0; r < 4; ++r)
                    sB[(mt * 16 + (quad << 2) + r) * STR_W + col] = f2bf(acc[mt][nt][r]);
            }
    }
    __syncthreads();  // B4: attn-out visible; vpT reads done

    // ---- y' = gelu(attn-out @ Wo^T + bo) -> sA ----
    {
        ZERO_ACC
        #pragma unroll 2
        for (int k0 = 0; k0 < DD; k0 += 32) {
            us8 a0 = *(const us8*)(sB + (l) * STR_W + k0 + koff);
            us8 a1 = *(const us8*)(sB + (16 + l) * STR_W + k0 + koff);
            us8 a2 = *(const us8*)(sB + (32 + l) * STR_W + k0 + koff);
            us8 a3 = *(const us8*)(sB + (48 + l) * STR_W + k0 + koff);
            us8 b0 = *(const us8*)(Wo + (n0 + l) * DD + k0 + koff);
            us8 b1 = *(const us8*)(Wo + (n0 + 16 + l) * DD + k0 + koff);
            us8 b2 = *(const us8*)(Wo + (n0 + 32 + l) * DD + k0 + koff);
            us8 b3 = *(const us8*)(Wo + (n0 + 48 + l) * DD + k0 + koff);
            MFMA(acc[0][0], a0, b0); MFMA(acc[0][1], a0, b1);
            MFMA(acc[0][2], a0, b2); MFMA(acc[0][3], a0, b3);
            MFMA(acc[1][0], a1, b0); MFMA(acc[1][1], a1, b1);
            MFMA(acc[1][2], a1, b2); MFMA(acc[1][3], a1, b3);
            MFMA(acc[2][0], a2, b0); MFMA(acc[2][1], a2, b1);
            MFMA(acc[2][2], a2, b2); MFMA(acc[2][3], a2, b3);
            MFMA(acc[3][0], a3, b0); MFMA(acc[3][1], a3, b1);
            MFMA(acc[3][2], a3, b2); MFMA(acc[3][3], a3, b3);
        }
        #pragma unroll
        for (int nt = 0; nt < 4; ++nt) {
            int col = n0 + nt * 16 + l;
            float bias = bo[col];
            #pragma unroll
            for (int mt = 0; mt < 4; ++mt) {
                #pragma unroll
                for (int r = 0; r < 4; ++r) {
                    int row = mt * 16 + (quad << 2) + r;
                    float y = acc[mt][nt][r] + bias;
                    float g = 0.5f * y * (1.0f + erff(y * 0.7071067811865475f));
                    sA[row * STR_W + col] = f2bf(g);
                }
            }
        }
    }
    __syncthreads();  // B5: gelu-out visible

    // ---- coalesced epilogue: out = gelu-out + q ----
    #pragma unroll
    for (int s = 0; s < 16; ++s) {
        int f = s * 1024 + tid * 4;
        int row = f >> 8, col = f & 255;
        us4 gb = *(const us4*)(sA + row * STR_W + col);
        float4 qv = *(const float4*)(qg + f);
        float4 o;
        o.x = bf2f(gb[0]) + qv.x;
        o.y = bf2f(gb[1]) + qv.y;
        o.z = bf2f(gb[2]) + qv.z;
        o.w = bf2f(gb[3]) + qv.w;
        *(float4*)(og + f) = o;
    }
}

extern "C" void kernel_launch(void* const* d_in, const int* in_sizes, int n_in,
                              void* d_out, int out_size, void* d_ws, size_t ws_size,
                              hipStream_t stream) {
    const float* q  = (const float*)d_in[0];
    const float* k  = (const float*)d_in[1];
    const float* v  = (const float*)d_in[2];
    const float* Wq = (const float*)d_in[3];
    const float* Wk = (const float*)d_in[4];
    const float* Wv = (const float*)d_in[5];
    const float* Wo = (const float*)d_in[6];
    const float* bo = (const float*)d_in[7];
    unsigned short* ws = (unsigned short*)d_ws;  // 4x 65536 bf16 weights + 16384 f32 pos-enc

    prep_kernel<<<64, 256, 0, stream>>>(Wq, Wk, Wv, Wo, ws);
    attn_kernel<<<NVIEWS, 256, 0, stream>>>(q, k, v, ws, bo, (float*)d_out);
}

// Round 5
// 333.773 us; speedup vs baseline: 1.3485x; 1.1204x over previous
//
#include <hip/hip_runtime.h>
#include <math.h>

#define NVIEWS 1024
#define SS 64
#define DD 256
#define KAUG 320   // augmented K: 256 W-cols + 64 one-hot pe cols

typedef __bf16 bf16x8 __attribute__((ext_vector_type(8)));
typedef float f32x4 __attribute__((ext_vector_type(4)));
typedef unsigned short us4 __attribute__((ext_vector_type(4)));
typedef unsigned short us8 __attribute__((ext_vector_type(8)));
typedef unsigned int u32x4 __attribute__((ext_vector_type(4)));

// LDS layout (bytes). Strides 16B-aligned; row shift = 4 banks -> worst 2-way (free).
#define STR_W 264   // [64][256] bf16 buffers: row = 528B
#define STR_T 72    // [256][64] vpT and [64][64] P: row = 144B
#define OFF_A 0      // qp (33792) -> vpT (36864) -> gelu-out (33792)
#define OFF_B 36864  // kp (33792) -> attn-out (33792)
#define OFF_P 70656  // P (9216)
#define LDS_TOTAL 79872

// ws layout (shorts): Wq' [256][320] @0, Wk' @81920, Wv' @163840, Wo [256][256] @245760
#define WS_WQ 0
#define WS_WK 81920
#define WS_WV 163840
#define WS_WO 245760

__device__ __forceinline__ unsigned short f2bf(float f) {
    return (unsigned short)((__builtin_bit_cast(unsigned int, f) + 0x8000u) >> 16);
}
__device__ __forceinline__ float bf2f(unsigned short h) {
    unsigned int u = ((unsigned int)h) << 16;
    return __builtin_bit_cast(float, u);
}
__device__ __forceinline__ unsigned int packbf2(float lo, float hi) {
    unsigned int ul = __builtin_bit_cast(unsigned int, lo) + 0x8000u;
    unsigned int uh = __builtin_bit_cast(unsigned int, hi) + 0x8000u;
    return __builtin_amdgcn_perm(uh, ul, 0x07060302u);
}

__global__ void prep_kernel(const float* __restrict__ Wq, const float* __restrict__ Wk,
                            const float* __restrict__ Wv, const float* __restrict__ Wo,
                            unsigned short* __restrict__ ws) {
    int t = blockIdx.x * blockDim.x + threadIdx.x;  // 65536 threads
    int n = t >> 8, k = t & 255;
    ws[WS_WQ + n * KAUG + k] = f2bf(Wq[t]);
    ws[WS_WK + n * KAUG + k] = f2bf(Wk[t]);
    ws[WS_WV + n * KAUG + k] = f2bf(Wv[t]);
    ws[WS_WO + t]            = f2bf(Wo[t]);
    if (t < SS * DD) {
        // pe[j][n]: j = sample 0..63, n = dim 0..255
        int j = t >> 8, d = t & 255;
        float ang = (float)j * expf(-((float)(d >> 1)) * (9.210340371976184f / 128.0f));
        unsigned short pb = f2bf((d & 1) ? cosf(ang) : sinf(ang));
        ws[WS_WQ + d * KAUG + 256 + j] = pb;
        ws[WS_WK + d * KAUG + 256 + j] = pb;
        ws[WS_WV + d * KAUG + 256 + j] = pb;
    }
}

// A-fragment: 8 consecutive fp32 -> bf16x8 via 2 float4 loads + 4 v_perm packs
#define LOAD_A_FRAG(dst, Xp, row, kk)                                          \
    {                                                                          \
        const float4* _p = (const float4*)((Xp) + (row) * DD + (kk));          \
        float4 _a = _p[0], _b = _p[1];                                         \
        u32x4 _w;                                                              \
        _w[0] = packbf2(_a.x, _a.y); _w[1] = packbf2(_a.z, _a.w);              \
        _w[2] = packbf2(_b.x, _b.y); _w[3] = packbf2(_b.z, _b.w);              \
        dst = __builtin_bit_cast(us8, _w);                                     \
    }

#define MFMA(d, a, b) d = __builtin_amdgcn_mfma_f32_16x16x32_bf16(             \
        __builtin_bit_cast(bf16x8, a), __builtin_bit_cast(bf16x8, b), d, 0, 0, 0)

// Projection with pe folded in: acc[4][4], rows mt*16+.., cols n0+nt*16+..
// Main loop over X (K=256), then 2 augmented k-blocks with synthesized one-hot A.
#define PROJECT(Xp, Wp)                                                        \
    _Pragma("unroll 2")                                                        \
    for (int k0 = 0; k0 < DD; k0 += 32) {                                      \
        us8 af0, af1, af2, af3, bq0, bq1, bq2, bq3;                            \
        LOAD_A_FRAG(af0, Xp, l, k0 + koff);                                    \
        LOAD_A_FRAG(af1, Xp, 16 + l, k0 + koff);                               \
        LOAD_A_FRAG(af2, Xp, 32 + l, k0 + koff);                               \
        LOAD_A_FRAG(af3, Xp, 48 + l, k0 + koff);                               \
        bq0 = *(const us8*)((Wp) + (n0 + l) * KAUG + k0 + koff);               \
        bq1 = *(const us8*)((Wp) + (n0 + 16 + l) * KAUG + k0 + koff);          \
        bq2 = *(const us8*)((Wp) + (n0 + 32 + l) * KAUG + k0 + koff);          \
        bq3 = *(const us8*)((Wp) + (n0 + 48 + l) * KAUG + k0 + koff);          \
        MFMA(acc[0][0], af0, bq0); MFMA(acc[0][1], af0, bq1);                  \
        MFMA(acc[0][2], af0, bq2); MFMA(acc[0][3], af0, bq3);                  \
        MFMA(acc[1][0], af1, bq0); MFMA(acc[1][1], af1, bq1);                  \
        MFMA(acc[1][2], af1, bq2); MFMA(acc[1][3], af1, bq3);                  \
        MFMA(acc[2][0], af2, bq0); MFMA(acc[2][1], af2, bq1);                  \
        MFMA(acc[2][2], af2, bq2); MFMA(acc[2][3], af2, bq3);                  \
        MFMA(acc[3][0], af3, bq0); MFMA(acc[3][1], af3, bq1);                  \
        MFMA(acc[3][2], af3, bq2); MFMA(acc[3][3], af3, bq3);                  \
    }                                                                          \
    {                                                                          \
        /* augmented pe tail: j-block1 cols 256..287 (rows 0..31),             \
           j-block2 cols 288..319 (rows 32..63). A = one-hot (synthesized). */ \
        us8 p0 = *(const us8*)((Wp) + (n0 + l) * KAUG + 256 + koff);           \
        us8 p1 = *(const us8*)((Wp) + (n0 + 16 + l) * KAUG + 256 + koff);      \
        us8 p2 = *(const us8*)((Wp) + (n0 + 32 + l) * KAUG + 256 + koff);      \
        us8 p3 = *(const us8*)((Wp) + (n0 + 48 + l) * KAUG + 256 + koff);      \
        us8 r0 = *(const us8*)((Wp) + (n0 + l) * KAUG + 288 + koff);           \
        us8 r1 = *(const us8*)((Wp) + (n0 + 16 + l) * KAUG + 288 + koff);      \
        us8 r2 = *(const us8*)((Wp) + (n0 + 32 + l) * KAUG + 288 + koff);      \
        us8 r3 = *(const us8*)((Wp) + (n0 + 48 + l) * KAUG + 288 + koff);      \
        MFMA(acc[0][0], idA, p0); MFMA(acc[0][1], idA, p1);                    \
        MFMA(acc[0][2], idA, p2); MFMA(acc[0][3], idA, p3);                    \
        MFMA(acc[1][0], idB, p0); MFMA(acc[1][1], idB, p1);                    \
        MFMA(acc[1][2], idB, p2); MFMA(acc[1][3], idB, p3);                    \
        MFMA(acc[2][0], idA, r0); MFMA(acc[2][1], idA, r1);                    \
        MFMA(acc[2][2], idA, r2); MFMA(acc[2][3], idA, r3);                    \
        MFMA(acc[3][0], idB, r0); MFMA(acc[3][1], idB, r1);                    \
        MFMA(acc[3][2], idB, r2); MFMA(acc[3][3], idB, r3);                    \
    }

#define ZERO_ACC                                                               \
    _Pragma("unroll")                                                          \
    for (int _i = 0; _i < 4; ++_i)                                             \
        _Pragma("unroll")                                                      \
        for (int _j = 0; _j < 4; ++_j) acc[_i][_j] = (f32x4){0.f, 0.f, 0.f, 0.f};

// Store acc as bf16 into dst[64][STR_W] (pe already folded in)
#define STORE_C(dst)                                                           \
    _Pragma("unroll")                                                          \
    for (int mt = 0; mt < 4; ++mt)                                             \
        _Pragma("unroll")                                                      \
        for (int nt = 0; nt < 4; ++nt) {                                       \
            int col = n0 + nt * 16 + l;                                        \
            _Pragma("unroll")                                                  \
            for (int r = 0; r < 4; ++r)                                        \
                (dst)[(mt * 16 + (quad << 2) + r) * STR_W + col] = f2bf(acc[mt][nt][r]); \
        }

// 256 threads = 4 waves. Wave w: all 64 rows, cols w*64..w*64+63.
__global__ __launch_bounds__(256, 2)
void attn_kernel(const float* __restrict__ qg_, const float* __restrict__ kg_,
                 const float* __restrict__ vg_, const unsigned short* __restrict__ ws,
                 const float* __restrict__ bo, float* __restrict__ outg) {
    __shared__ __attribute__((aligned(16))) char smem[LDS_TOTAL];
    unsigned short* sA = (unsigned short*)(smem + OFF_A);  // qp -> vpT -> gelu-out
    unsigned short* sB = (unsigned short*)(smem + OFF_B);  // kp -> attn-out
    unsigned short* sP = (unsigned short*)(smem + OFF_P);

    const unsigned short* Wq = ws + WS_WQ;
    const unsigned short* Wk = ws + WS_WK;
    const unsigned short* Wv = ws + WS_WV;
    const unsigned short* Wo = ws + WS_WO;

    const int tid  = threadIdx.x;
    const int w    = tid >> 6;        // wave 0..3
    const int lane = tid & 63;
    const int quad = lane >> 4;
    const int l    = lane & 15;
    const int n0   = w << 6;          // this wave's 64-col chunk
    const int koff = quad << 3;

    // one-hot A fragments for the augmented pe tail (no loads):
    // idA: A[m_tile=l][j_local] = (j_local == l); idB: = (j_local == 16+l)
    unsigned int w1 = (l & 1) ? 0x3F800000u : 0x00003F80u;  // bf16 1.0 in hi/lo half
    int dw = (l >> 1) & 3;
    bool cA = (quad == (l >> 3));        // j_local = l in this quad's 8-col window
    bool cB = (quad == 2 + (l >> 3));    // j_local = 16+l
    u32x4 eA, eB;
    eA[0] = (cA && dw == 0) ? w1 : 0u; eA[1] = (cA && dw == 1) ? w1 : 0u;
    eA[2] = (cA && dw == 2) ? w1 : 0u; eA[3] = (cA && dw == 3) ? w1 : 0u;
    eB[0] = (cB && dw == 0) ? w1 : 0u; eB[1] = (cB && dw == 1) ? w1 : 0u;
    eB[2] = (cB && dw == 2) ? w1 : 0u; eB[3] = (cB && dw == 3) ? w1 : 0u;
    us8 idA = __builtin_bit_cast(us8, eA);
    us8 idB = __builtin_bit_cast(us8, eB);

    const size_t base = (size_t)blockIdx.x * (SS * DD);
    const float* qg = qg_ + base;
    const float* kg = kg_ + base;
    const float* vg = vg_ + base;
    float* og = outg + base;

    f32x4 acc[4][4];

    // ---- kp = k@Wk^T + pe -> sB ----
    ZERO_ACC
    PROJECT(kg, Wk)
    STORE_C(sB)

    // ---- qp = q@Wq^T + pe -> sA ----
    ZERO_ACC
    PROJECT(qg, Wq)
    STORE_C(sA)

    __syncthreads();  // B1

    // ---- S = qp@kp^T + softmax: wave w owns q-rows w*16..w*16+15 ----
    {
        f32x4 s0 = {0.f,0.f,0.f,0.f}, s1 = {0.f,0.f,0.f,0.f};
        f32x4 s2 = {0.f,0.f,0.f,0.f}, s3 = {0.f,0.f,0.f,0.f};
        #pragma unroll
        for (int k0 = 0; k0 < DD; k0 += 32) {
            us8 a  = *(const us8*)(sA + (w * 16 + l) * STR_W + k0 + koff);
            us8 b0 = *(const us8*)(sB + (l) * STR_W + k0 + koff);
            us8 b1 = *(const us8*)(sB + (16 + l) * STR_W + k0 + koff);
            us8 b2 = *(const us8*)(sB + (32 + l) * STR_W + k0 + koff);
            us8 b3 = *(const us8*)(sB + (48 + l) * STR_W + k0 + koff);
            MFMA(s0, a, b0); MFMA(s1, a, b1); MFMA(s2, a, b2); MFMA(s3, a, b3);
        }
        #pragma unroll
        for (int r = 0; r < 4; ++r) {
            float v0 = s0[r] * 0.0625f, v1 = s1[r] * 0.0625f;
            float v2 = s2[r] * 0.0625f, v3 = s3[r] * 0.0625f;
            float mx = fmaxf(fmaxf(v0, v1), fmaxf(v2, v3));
            #pragma unroll
            for (int d = 1; d <= 8; d <<= 1) mx = fmaxf(mx, __shfl_xor(mx, d));
            float e0 = __expf(v0 - mx), e1 = __expf(v1 - mx);
            float e2 = __expf(v2 - mx), e3 = __expf(v3 - mx);
            float sm = e0 + e1 + e2 + e3;
            #pragma unroll
            for (int d = 1; d <= 8; d <<= 1) sm += __shfl_xor(sm, d);
            float inv = 1.0f / sm;
            int row = w * 16 + (quad << 2) + r;
            sP[row * STR_T + l]      = f2bf(e0 * inv);
            sP[row * STR_T + 16 + l] = f2bf(e1 * inv);
            sP[row * STR_T + 32 + l] = f2bf(e2 * inv);
            sP[row * STR_T + 48 + l] = f2bf(e3 * inv);
        }
    }

    // ---- vp = v@Wv^T + pe (registers only until B2) ----
    ZERO_ACC
    PROJECT(vg, Wv)
    __syncthreads();  // B2: S-phase LDS reads done; sP complete
    // transpose-write vpT into sA [256][STR_T]
    #pragma unroll
    for (int mt = 0; mt < 4; ++mt)
        #pragma unroll
        for (int nt = 0; nt < 4; ++nt) {
            int col = n0 + nt * 16 + l;            // d index = vpT row
            int rbase = mt * 16 + (quad << 2);
            us4 pk;
            #pragma unroll
            for (int r = 0; r < 4; ++r)
                pk[r] = f2bf(acc[mt][nt][r]);
            *(us4*)(sA + col * STR_T + rbase) = pk;   // 8B transpose write
        }
    __syncthreads();  // B3: vpT visible

    // ---- attn-out = P @ vp -> sB ----
    {
        ZERO_ACC
        #pragma unroll
        for (int k0 = 0; k0 < 64; k0 += 32) {
            us8 a0 = *(const us8*)(sP + (l) * STR_T + k0 + koff);
            us8 a1 = *(const us8*)(sP + (16 + l) * STR_T + k0 + koff);
            us8 a2 = *(const us8*)(sP + (32 + l) * STR_T + k0 + koff);
            us8 a3 = *(const us8*)(sP + (48 + l) * STR_T + k0 + koff);
            us8 b0 = *(const us8*)(sA + (n0 + l) * STR_T + k0 + koff);
            us8 b1 = *(const us8*)(sA + (n0 + 16 + l) * STR_T + k0 + koff);
            us8 b2 = *(const us8*)(sA + (n0 + 32 + l) * STR_T + k0 + koff);
            us8 b3 = *(const us8*)(sA + (n0 + 48 + l) * STR_T + k0 + koff);
            MFMA(acc[0][0], a0, b0); MFMA(acc[0][1], a0, b1);
            MFMA(acc[0][2], a0, b2); MFMA(acc[0][3], a0, b3);
            MFMA(acc[1][0], a1, b0); MFMA(acc[1][1], a1, b1);
            MFMA(acc[1][2], a1, b2); MFMA(acc[1][3], a1, b3);
            MFMA(acc[2][0], a2, b0); MFMA(acc[2][1], a2, b1);
            MFMA(acc[2][2], a2, b2); MFMA(acc[2][3], a2, b3);
            MFMA(acc[3][0], a3, b0); MFMA(acc[3][1], a3, b1);
            MFMA(acc[3][2], a3, b2); MFMA(acc[3][3], a3, b3);
        }
        #pragma unroll
        for (int mt = 0; mt < 4; ++mt)
            #pragma unroll
            for (int nt = 0; nt < 4; ++nt) {
                int col = n0 + nt * 16 + l;
                #pragma unroll
                for (int r = 0; r < 4; ++r)
                    sB[(mt * 16 + (quad << 2) + r) * STR_W + col] = f2bf(acc[mt][nt][r]);
            }
    }
    __syncthreads();  // B4: attn-out visible; vpT reads done

    // ---- y' = gelu(attn-out @ Wo^T + bo) -> sA ----
    {
        ZERO_ACC
        #pragma unroll 2
        for (int k0 = 0; k0 < DD; k0 += 32) {
            us8 a0 = *(const us8*)(sB + (l) * STR_W + k0 + koff);
            us8 a1 = *(const us8*)(sB + (16 + l) * STR_W + k0 + koff);
            us8 a2 = *(const us8*)(sB + (32 + l) * STR_W + k0 + koff);
            us8 a3 = *(const us8*)(sB + (48 + l) * STR_W + k0 + koff);
            us8 b0 = *(const us8*)(Wo + (n0 + l) * DD + k0 + koff);
            us8 b1 = *(const us8*)(Wo + (n0 + 16 + l) * DD + k0 + koff);
            us8 b2 = *(const us8*)(Wo + (n0 + 32 + l) * DD + k0 + koff);
            us8 b3 = *(const us8*)(Wo + (n0 + 48 + l) * DD + k0 + koff);
            MFMA(acc[0][0], a0, b0); MFMA(acc[0][1], a0, b1);
            MFMA(acc[0][2], a0, b2); MFMA(acc[0][3], a0, b3);
            MFMA(acc[1][0], a1, b0); MFMA(acc[1][1], a1, b1);
            MFMA(acc[1][2], a1, b2); MFMA(acc[1][3], a1, b3);
            MFMA(acc[2][0], a2, b0); MFMA(acc[2][1], a2, b1);
            MFMA(acc[2][2], a2, b2); MFMA(acc[2][3], a2, b3);
            MFMA(acc[3][0], a3, b0); MFMA(acc[3][1], a3, b1);
            MFMA(acc[3][2], a3, b2); MFMA(acc[3][3], a3, b3);
        }
        #pragma unroll
        for (int nt = 0; nt < 4; ++nt) {
            int col = n0 + nt * 16 + l;
            float bias = bo[col];
            #pragma unroll
            for (int mt = 0; mt < 4; ++mt) {
                #pragma unroll
                for (int r = 0; r < 4; ++r) {
                    int row = mt * 16 + (quad << 2) + r;
                    float y = acc[mt][nt][r] + bias;
                    // tanh-approx GELU: 0.5y(1+tanh(u)) = y*sigmoid(2u), max dev ~3e-4
                    float u = 1.5957691216f * y * (1.0f + 0.044715f * y * y);
                    float g = y / (1.0f + __expf(-u));
                    sA[row * STR_W + col] = f2bf(g);
                }
            }
        }
    }
    __syncthreads();  // B5: gelu-out visible

    // ---- coalesced epilogue: out = gelu-out + q ----
    #pragma unroll
    for (int s = 0; s < 16; ++s) {
        int f = s * 1024 + tid * 4;
        int row = f >> 8, col = f & 255;
        us4 gb = *(const us4*)(sA + row * STR_W + col);
        float4 qv = *(const float4*)(qg + f);
        float4 o;
        o.x = bf2f(gb[0]) + qv.x;
        o.y = bf2f(gb[1]) + qv.y;
        o.z = bf2f(gb[2]) + qv.z;
        o.w = bf2f(gb[3]) + qv.w;
        *(float4*)(og + f) = o;
    }
}

extern "C" void kernel_launch(void* const* d_in, const int* in_sizes, int n_in,
                              void* d_out, int out_size, void* d_ws, size_t ws_size,
                              hipStream_t stream) {
    const float* q  = (const float*)d_in[0];
    const float* k  = (const float*)d_in[1];
    const float* v  = (const float*)d_in[2];
    const float* Wq = (const float*)d_in[3];
    const float* Wk = (const float*)d_in[4];
    const float* Wv = (const float*)d_in[5];
    const float* Wo = (const float*)d_in[6];
    const float* bo = (const float*)d_in[7];
    unsigned short* ws = (unsigned short*)d_ws;  // augmented bf16 weights (pe folded)

    prep_kernel<<<256, 256, 0, stream>>>(Wq, Wk, Wv, Wo, ws);
    attn_kernel<<<NVIEWS, 256, 0, stream>>>(q, k, v, ws, bo, (float*)d_out);
}